// Round 9
// baseline (317.502 us; speedup 1.0000x reference)
//
#include <hip/hip_runtime.h>
#include <math.h>

#define L_LEN 2001
#define CCH 224           // positions per chunk per row
#define NCH 9             // chunks: 9*224 = 2016 >= 2001
#define XRECS 256         // xs records per chunk (CCH+32) -> exactly 4 per lane
#define YRECS 240         // y1 records per chunk (CCH+16)
#define NTC 14            // conv2 tiles per chunk (CCH/16 outputs)

typedef __attribute__((ext_vector_type(8))) short bf16x8;
typedef __attribute__((ext_vector_type(4))) float f32x4;
typedef __attribute__((ext_vector_type(16))) float f32x16;
typedef __attribute__((ext_vector_type(4), aligned(4))) float f32x4u;  // unaligned-tolerant
#if __has_builtin(__builtin_amdgcn_cvt_pk_bf16_f32)
typedef __attribute__((ext_vector_type(2))) __bf16 bf16x2_t;
#endif

union FragU { unsigned u[4]; uint2 u2[2]; uint4 u4; bf16x8 v; };

__device__ __forceinline__ unsigned short f2bf(float f) {
    unsigned u = __builtin_bit_cast(unsigned, f);
    u += 0x7fffu + ((u >> 16) & 1u);
    return (unsigned short)(u >> 16);
}
// pack two fp32 -> bf16 pair (RNE), hi<<16 | lo
__device__ __forceinline__ unsigned bfpack(float lo, float hi) {
#if __has_builtin(__builtin_amdgcn_cvt_pk_bf16_f32)
    bf16x2_t r = __builtin_amdgcn_cvt_pk_bf16_f32(lo, hi);   // S0 -> [15:0]
    return __builtin_bit_cast(unsigned, r);
#else
    unsigned ul = __builtin_bit_cast(unsigned, lo);
    unsigned uh = __builtin_bit_cast(unsigned, hi);
    ul += 0x7fffu + ((ul >> 16) & 1u);
    uh += 0x7fffu + ((uh >> 16) & 1u);
    return __builtin_amdgcn_perm(uh, ul, 0x07060302);
#endif
}
__device__ __forceinline__ float fast_rcp(float x) { return __builtin_amdgcn_rcpf(x); }
__device__ __forceinline__ float fexp2(float x) {
#if __has_builtin(__builtin_amdgcn_exp2f)
    return __builtin_amdgcn_exp2f(x);
#else
    return __expf(x * 0.69314718f);
#endif
}

// Wave-per-row, zero barriers (R3); 32x32 conv1 + vectorized stage A (R4);
// T14 register prefetch (R5/R6). R9: TWO ROWS PER WAVE -- each wave runs two
// independent rows through identical stage phases (A0,A1 | B0,B1 | C0,C1).
// Rationale: across R6-R8 VALU-busy-equivalent time is invariant (~70us) vs
// wall ~121us with no pipe >58% -- intra-wave dependency stalls. Doubling
// per-wave independent work fills issue slots; unlike R8's A||C mix, each
// phase's DS ops are homogeneous so in-order lgkmcnt doesn't false-couple.
// Block = 128 thr (2 waves, 4 rows): grid stays 2048, LDS 23 KB/block.
__global__ __launch_bounds__(128, 3)
void taylor_cnn_v14_wave2(const float* __restrict__ phase, const float* __restrict__ primary,
                          const float* __restrict__ secondary, const float* __restrict__ oddeven,
                          const float* __restrict__ pA, const float* __restrict__ pBp,
                          const float* __restrict__ pT0,
                          const float* __restrict__ bng, const float* __restrict__ bnb,
                          const float* __restrict__ bnm, const float* __restrict__ bnv,
                          const float* __restrict__ w1, const float* __restrict__ b1,
                          const float* __restrict__ w2, const float* __restrict__ b2,
                          const float* __restrict__ fcw, const float* __restrict__ fcb,
                          float* __restrict__ out, int nrows)
{
    // per-wave, per-row LDS slices (no cross-wave sharing, no barriers)
    __shared__ __align__(16) unsigned int xs_i[2][2][XRECS * 2];   // 8.0 KB
    __shared__ __align__(16) unsigned int y1_i[2][2][YRECS * 4];   // 15.4 KB

    const int tid = threadIdx.x;
    const int l   = tid & 63;
    const int wid = tid >> 6;                 // 0..1
    const int row0 = blockIdx.x * 4 + wid * 2;
    if (row0 >= nrows) return;                // wave-uniform; legal (no barriers)
    const bool r1ok = (row0 + 1 < nrows);
    const long baseA[2] = { (long)row0 * L_LEN,
                            (long)(r1ok ? row0 + 1 : row0) * L_LEN };

    unsigned int* xsA[2] = { xs_i[wid][0], xs_i[wid][1] };
    unsigned int* y1A[2] = { y1_i[wid][0], y1_i[wid][1] };

    const int n    = l & 15;     // 16x16 MFMA column (conv2 / tail tile)
    const int quad = l >> 4;     // 16x16 MFMA k-block / D row-quad
    const int c    = l & 31;     // 32x32 MFMA column (conv1)
    const int h    = l >> 5;     // 32x32 MFMA half

    const float A  = pA[0];
    const float Bp = pBp[0];
    const float t0 = pT0[0];
    const float A_abs = fabsf(A) + 1e-8f;
    const float rAabs = 1.0f / A_abs;
    const float nBp  = -Bp;
    const float cExp = -72.134766f * rAabs;   // -50*log2(e)*rAabs

    float inv1, inv2, inv3, gInv0, off0, off1, off2, off3;
    {
        float iv0 = bng[0] / sqrtf(bnv[0] + 1e-5f);
        float iv1 = bng[1] / sqrtf(bnv[1] + 1e-5f);
        float iv2 = bng[2] / sqrtf(bnv[2] + 1e-5f);
        float iv3 = bng[3] / sqrtf(bnv[3] + 1e-5f);
        gInv0 = -A * iv0;                     // gate = relu(1-Bp*d^2); x0 = g*(-A*iv0)+off0
        inv1 = iv1; inv2 = iv2; inv3 = iv3;
        off0 = bnb[0] - bnm[0] * iv0;
        off1 = bnb[1] - bnm[1] * iv1;
        off2 = bnb[2] - bnm[2] * iv2;
        off3 = bnb[3] - bnm[3] * iv3;
    }

    // ---- conv1 32x32x16 A-fragments: row = l&31 (oc), k = 8*h + j ----
    bf16x8 a32_0, a32_1;
#pragma unroll
    for (int jp = 0; jp < 8; ++jp) {
        int ch_  = jp & 3;
        int tap0 = (jp >> 2) + 2 * h;
        int tap1 = 4 + (jp >> 2) + 2 * h;
        float v0 = (c < 8) ? w1[(c * 4 + ch_) * 7 + tap0] : 0.0f;
        float v1 = (c < 8 && tap1 < 7) ? w1[(c * 4 + ch_) * 7 + tap1] : 0.0f;
        a32_0[jp] = (short)f2bf(v0);
        a32_1[jp] = (short)f2bf(v1);
    }
    f32x16 cb32;
#pragma unroll
    for (int r = 0; r < 16; ++r)
        cb32[r] = (r < 4) ? b1[(r & 3) + 4 * h] : 0.0f;

    // ---- 16x16x32 conv1 fragment (tail tile, records 224..239) ----
    bf16x8 a1;
#pragma unroll
    for (int jp = 0; jp < 8; ++jp) {
        int j = quad + 4 * (jp >> 2);
        int cc = jp & 3;
        float v = (n < 8 && j < 7) ? w1[(n * 4 + cc) * 7 + j] : 0.0f;
        a1[jp] = (short)f2bf(v);
    }
    // ---- conv2 fragments ----
    bf16x8 a20, a21;
#pragma unroll
    for (int jp = 0; jp < 8; ++jp) {
        float v0 = w2[(n * 8 + jp) * 5 + quad];
        float v1 = (quad + 4 < 5) ? w2[(n * 8 + jp) * 5 + quad + 4] : 0.0f;
        a20[jp] = (short)f2bf(v0);
        a21[jp] = (short)f2bf(v1);
    }
    f32x4 cb1, cb2;
#pragma unroll
    for (int r = 0; r < 4; ++r) {
        cb1[r] = b1[(quad * 4 + r) & 7];
        cb2[r] = b2[quad * 4 + r];
    }
    float fw0 = fcw[quad * 4 + 0];
    float fw1 = fcw[quad * 4 + 1];
    float fw2 = fcw[quad * 4 + 2];
    float fw3 = fcw[quad * 4 + 3];

    float s_dip[2] = {0.f, 0.f}, s_fb[2] = {0.f, 0.f};
    float mAcc[2][4] = {{0.f, 0.f, 0.f, 0.f}, {0.f, 0.f, 0.f, 0.f}};

    // trapz AUC: 200 samples per row -> 4 per lane (last masked to l<8)
    float s_auc[2] = {0.f, 0.f};
#pragma unroll
    for (int r = 0; r < 2; ++r) {
#pragma unroll
        for (int k = 0; k < 4; ++k) {
            int s = l + 64 * k;
            if (k < 3 || l < 8) {
                float pos = (float)s * (2000.0f / 199.0f);
                int i0 = (int)pos;
                if (i0 > 2000) i0 = 2000;
                int i1 = (i0 + 1 < L_LEN) ? i0 + 1 : 2000;
                float w  = pos - (float)i0;
                float d0 = fmaxf(-primary[baseA[r] + i0], 0.f);
                float d1 = fmaxf(-primary[baseA[r] + i1], 0.f);
                float v  = d0 * (1.0f - w) + d1 * w;
                float wt = (s == 0 || s == 199) ? 0.5f : 1.0f;
                s_auc[r] += v * wt;
            }
        }
    }

    const float coreMask = (l >= 4 && l < 60) ? 1.0f : 0.0f;   // records 16..239

    // ---- stage A scalar record processor (last chunk only) ----
    auto aRec = [&](unsigned int* xsBuf, long base, int m, int p, bool valid, bool core,
                    float& dipS, float& fbS) {
        float ph = phase[base + p];
        float pf = primary[base + p];
        float sf = secondary[base + p];
        float oe = oddeven[base + p];
        float dd = ph - t0;
        float g  = fmaxf(fmaf(dd * dd, nBp, 1.0f), 0.0f);
        float x0 = fmaf(g,  gInv0, off0);
        float x1 = fmaf(pf, inv1, off1);
        float x2 = fmaf(sf, inv2, off2);
        float x3 = fmaf(oe, inv3, off3);
        unsigned d0 = bfpack(x0, x1);
        unsigned d1 = bfpack(x2, x3);
        if (!valid) { d0 = 0u; d1 = 0u; }
        *(uint2*)&xsBuf[2 * m] = make_uint2(d0, d1);
        float depth = fmaxf(-pf, 0.0f);
        float e   = fexp2(depth * cExp);
        float dip = fast_rcp(fmaf(e, 148.413159f, 1.0f));
        float fb  = fast_rcp(fmaf(e, 2.35385267e17f, 1.0f));
        if (!core) { dip = 0.f; fb = 0.f; }
        dipS += dip;
        fbS  += fb;
    };

    // ---- vector stage A body: consume regs -> write xsBuf ----
    auto aVec = [&](unsigned int* xsBuf, const f32x4u& vph, const f32x4u& vpf,
                    const f32x4u& vsf, const f32x4u& voe, bool zeroLow,
                    float& dipS, float& fbS) {
        unsigned dw[8];
        float dipA = 0.f, fbA = 0.f;
#pragma unroll
        for (int j = 0; j < 4; ++j) {
            float dd = vph[j] - t0;
            float g  = fmaxf(fmaf(dd * dd, nBp, 1.0f), 0.0f);
            float x0 = fmaf(g,      gInv0, off0);
            float x1 = fmaf(vpf[j], inv1,  off1);
            float x2 = fmaf(vsf[j], inv2,  off2);
            float x3 = fmaf(voe[j], inv3,  off3);
            dw[2 * j]     = bfpack(x0, x1);
            dw[2 * j + 1] = bfpack(x2, x3);
            float depth = fmaxf(-vpf[j], 0.0f);
            float e   = fexp2(depth * cExp);
            float dip = fast_rcp(fmaf(e, 148.413159f, 1.0f));
            float fb  = fast_rcp(fmaf(e, 2.35385267e17f, 1.0f));
            dipA += dip;
            fbA  += fb;
        }
        if (zeroLow && l < 4) {               // records 0..15 = positions < 0
#pragma unroll
            for (int j = 0; j < 8; ++j) dw[j] = 0u;
        }
        *(uint4*)&xsBuf[8 * l]     = make_uint4(dw[0], dw[1], dw[2], dw[3]);
        *(uint4*)&xsBuf[8 * l + 4] = make_uint4(dw[4], dw[5], dw[6], dw[7]);
        dipS = fmaf(dipA, coreMask, dipS);
        fbS  = fmaf(fbA,  coreMask, fbS);
    };

    // ---- stage B: conv1 from xsBuf -> y1Buf ----
    auto stageB = [&](const unsigned int* xsBuf, unsigned int* y1Buf,
                      bool loZero, bool hiMask, bool tailZero) {
        const int cb = c + 2 * h + 5;
#pragma unroll 2
        for (int T = 0; T < 7; ++T) {
            const int R0 = 32 * T + cb;
            FragU b0, b1f;
            b0.u2[0]  = *(const uint2*)&xsBuf[2 * R0];
            b0.u2[1]  = *(const uint2*)&xsBuf[2 * R0 + 2];
            b1f.u2[0] = *(const uint2*)&xsBuf[2 * R0 + 8];
            b1f.u2[1] = *(const uint2*)&xsBuf[2 * R0 + 10];
            f32x16 d = __builtin_amdgcn_mfma_f32_32x32x16_bf16(a32_0, b0.v,  cb32, 0, 0, 0);
            d        = __builtin_amdgcn_mfma_f32_32x32x16_bf16(a32_1, b1f.v, d,    0, 0, 0);
            unsigned w0  = bfpack(fmaxf(d[0], 0.f), fmaxf(d[1], 0.f));
            unsigned w1_ = bfpack(fmaxf(d[2], 0.f), fmaxf(d[3], 0.f));
            if (loZero && T == 0) { if (c < 8)  { w0 = 0u; w1_ = 0u; } }  // pos < 0
            if (hiMask && T == 6) { if (c > 24) { w0 = 0u; w1_ = 0u; } }  // pos > 2000
            *(uint2*)&y1Buf[4 * (32 * T + c) + 2 * h] = make_uint2(w0, w1_);
        }
        // tail: y1 records 224..239
        if (!tailZero) {
            int qb = 224 + n + quad + 5;
            FragU bu;
            bu.u2[0] = *(const uint2*)&xsBuf[2 * qb];
            bu.u2[1] = *(const uint2*)&xsBuf[2 * (qb + 4)];
            f32x4 d = __builtin_amdgcn_mfma_f32_16x16x32_bf16(a1, bu.v, cb1, 0, 0, 0);
            if (l < 32) {
                unsigned w0  = bfpack(fmaxf(d[0], 0.f), fmaxf(d[1], 0.f));
                unsigned w1_ = bfpack(fmaxf(d[2], 0.f), fmaxf(d[3], 0.f));
                *(uint2*)&y1Buf[4 * (224 + n) + 2 * quad] = make_uint2(w0, w1_);
            }
        } else {
            if (l < 32)
                *(uint2*)&y1Buf[4 * (224 + n) + 2 * quad] = make_uint2(0u, 0u);
        }
    };

    // ---- stage C: conv2 from y1Buf, accumulate channel sums ----
    auto stageC = [&](const unsigned int* y1Buf, float (&mm)[4], int maskT) {
#pragma unroll 2
        for (int t = 0; t < NTC; ++t) {
            int q = 16 * t + n + quad + 6;
            FragU u0, u1;
            u0.u4 = *(const uint4*)&y1Buf[4 * q];
            u1.u4 = *(const uint4*)&y1Buf[4 * (q + 4)];
            f32x4 d = __builtin_amdgcn_mfma_f32_16x16x32_bf16(a20, u0.v, cb2, 0, 0, 0);
            d = __builtin_amdgcn_mfma_f32_16x16x32_bf16(a21, u1.v, d, 0, 0, 0);
            if (t == maskT) {                 // outputs 2000..2015: only n==0 valid
                float msk = (n == 0) ? 1.0f : 0.0f;
                mm[0] = fmaf(fmaxf(d[0], 0.f), msk, mm[0]);
                mm[1] = fmaf(fmaxf(d[1], 0.f), msk, mm[1]);
                mm[2] = fmaf(fmaxf(d[2], 0.f), msk, mm[2]);
                mm[3] = fmaf(fmaxf(d[3], 0.f), msk, mm[3]);
            } else {
                mm[0] += fmaxf(d[0], 0.f);
                mm[1] += fmaxf(d[1], 0.f);
                mm[2] += fmaxf(d[2], 0.f);
                mm[3] += fmaxf(d[3], 0.f);
            }
        }
    };

    // ---- T14 prefetch: preload chunk 0 (both rows) ----
    f32x4u ph4[2], pf4[2], sf4[2], oe4[2];
#pragma unroll
    for (int r = 0; r < 2; ++r) {
        int p0 = 4 * l - 16; if (p0 < 0) p0 = 0;
        ph4[r] = *(const f32x4u*)&phase[baseA[r] + p0];
        pf4[r] = *(const f32x4u*)&primary[baseA[r] + p0];
        sf4[r] = *(const f32x4u*)&secondary[baseA[r] + p0];
        oe4[r] = *(const f32x4u*)&oddeven[baseA[r] + p0];
    }

    // ---- vector chunks 0..7: {issue next loads} A0 A1 | B0 B1 | C0 C1 ----
#pragma unroll 1
    for (int ch = 0; ch < NCH - 1; ++ch) {
        const bool isFirst = (ch == 0);

        f32x4u nph[2], npf[2], nsf[2], noe[2];
        if (ch < NCH - 2) {
#pragma unroll
            for (int r = 0; r < 2; ++r) {
                const long pn = baseA[r] + ((ch + 1) * CCH - 16 + 4 * l);
                nph[r] = *(const f32x4u*)&phase[pn];
                npf[r] = *(const f32x4u*)&primary[pn];
                nsf[r] = *(const f32x4u*)&secondary[pn];
                noe[r] = *(const f32x4u*)&oddeven[pn];
            }
        } else {
#pragma unroll
            for (int r = 0; r < 2; ++r) {
                nph[r] = ph4[r]; npf[r] = pf4[r]; nsf[r] = sf4[r]; noe[r] = oe4[r];  // dead
            }
        }

#pragma unroll
        for (int r = 0; r < 2; ++r)
            aVec(xsA[r], ph4[r], pf4[r], sf4[r], oe4[r], isFirst, s_dip[r], s_fb[r]);

#pragma unroll
        for (int r = 0; r < 2; ++r)
            stageB(xsA[r], y1A[r], isFirst, false, false);

#pragma unroll
        for (int r = 0; r < 2; ++r)
            stageC(y1A[r], mAcc[r], -1);

#pragma unroll
        for (int r = 0; r < 2; ++r) {
            ph4[r] = nph[r]; pf4[r] = npf[r]; sf4[r] = nsf[r]; oe4[r] = noe[r];
        }
    }

    // ---- last chunk (ch = 8): scalar A, straddle-masked B, masked C ----
    {
        const int pb = (NCH - 1) * CCH - 16;   // 1776
        bool co0 = (l >= 16);
        int  p3  = pb + l + 192;
        bool v3  = (l < 33);                   // p <= 2000
        bool co3 = v3 && (l < 48);
        if (p3 > 2000) p3 = 2000;
#pragma unroll
        for (int r = 0; r < 2; ++r) {
            aRec(xsA[r], baseA[r], l,        pb + l,       true, co0, s_dip[r], s_fb[r]);
            aRec(xsA[r], baseA[r], l + 64,   pb + l + 64,  true, true, s_dip[r], s_fb[r]);
            aRec(xsA[r], baseA[r], l + 128,  pb + l + 128, true, true, s_dip[r], s_fb[r]);
            aRec(xsA[r], baseA[r], l + 192,  p3,           v3,   co3,  s_dip[r], s_fb[r]);
        }
#pragma unroll
        for (int r = 0; r < 2; ++r)
            stageB(xsA[r], y1A[r], false, true, true);
#pragma unroll
        for (int r = 0; r < 2; ++r)
            stageC(y1A[r], mAcc[r], 13);
    }

    // ---- per-wave reductions + epilogue (per row) ----
#pragma unroll
    for (int r = 0; r < 2; ++r) {
        float m0 = mAcc[r][0], m1 = mAcc[r][1], m2 = mAcc[r][2], m3 = mAcc[r][3];
#pragma unroll
        for (int dlt = 8; dlt >= 1; dlt >>= 1) {
            m0 += __shfl_xor(m0, dlt);
            m1 += __shfl_xor(m1, dlt);
            m2 += __shfl_xor(m2, dlt);
            m3 += __shfl_xor(m3, dlt);
        }
        float part = m0 * fw0 + m1 * fw1 + m2 * fw2 + m3 * fw3;
        part = (n == 0) ? part : 0.0f;
        part += __shfl_xor(part, 16);
        part += __shfl_xor(part, 32);
        float sd = s_dip[r], sf = s_fb[r], sa = s_auc[r];
#pragma unroll
        for (int dlt = 32; dlt >= 1; dlt >>= 1) {
            sd += __shfl_xor(sd, dlt);
            sf += __shfl_xor(sf, dlt);
            sa += __shfl_xor(sa, dlt);
        }
        if (l == 0 && (r == 0 || r1ok)) {
            float Sing = sd - sf;                   // sum(ing) = sum(dip) - sum(fb)
            float logit = fcb[0] + part * (1.0f / 2001.0f);
            float auc_raw  = (float)(2.0 / 199.0) * sa;
            float auc_norm = auc_raw / A_abs;
            float m_ing = Sing / 2001.0f;
            float m_fb  = sf / 2001.0f;
            float t14   = sd / 2001.0f + 1e-8f;     // (Sing+Sfb) == Sdip
            float t12   = m_ing / t14;

            logit += Bp       * fcw[16]
                   + auc_raw  * fcw[17]
                   + auc_norm * fcw[18]
                   + t12      * fcw[19]
                   + m_fb     * fcw[20];

            out[row0 + r] = 1.0f / (1.0f + expf(-logit));
        }
    }
}

extern "C" void kernel_launch(void* const* d_in, const int* in_sizes, int n_in,
                              void* d_out, int out_size, void* d_ws, size_t ws_size,
                              hipStream_t stream) {
    const float* phase     = (const float*)d_in[0];
    const float* primary   = (const float*)d_in[1];
    const float* secondary = (const float*)d_in[2];
    const float* oddeven   = (const float*)d_in[3];
    const float* pA        = (const float*)d_in[4];
    const float* pBp       = (const float*)d_in[5];
    const float* pT0       = (const float*)d_in[6];
    const float* bng       = (const float*)d_in[7];
    const float* bnb       = (const float*)d_in[8];
    const float* bnm       = (const float*)d_in[9];
    const float* bnv       = (const float*)d_in[10];
    const float* w1        = (const float*)d_in[11];
    const float* b1        = (const float*)d_in[12];
    const float* w2        = (const float*)d_in[13];
    const float* b2        = (const float*)d_in[14];
    const float* fcw       = (const float*)d_in[15];
    const float* fcb       = (const float*)d_in[16];
    float* out = (float*)d_out;

    int nrows = in_sizes[0] / L_LEN;   // 8192
    dim3 grid((nrows + 3) / 4), block(128);
    hipLaunchKernelGGL(taylor_cnn_v14_wave2, grid, block, 0, stream,
                       phase, primary, secondary, oddeven, pA, pBp, pT0,
                       bng, bnb, bnm, bnv, w1, b1, w2, b2, fcw, fcb, out, nrows);
}

// Round 10
// 284.432 us; speedup vs baseline: 1.1163x; 1.1163x over previous
//
#include <hip/hip_runtime.h>
#include <math.h>

#define L_LEN 2001
#define CCH 224           // positions per chunk per wave
#define NCH 9             // chunks: 9*224 = 2016 >= 2001
#define XRECS 256         // xs records per chunk (CCH+32) -> exactly 4 per lane
#define YRECS 240         // y1 records per chunk (CCH+16)
#define NTC 14            // conv2 tiles per chunk (CCH/16 outputs)

typedef __attribute__((ext_vector_type(8))) short bf16x8;
typedef __attribute__((ext_vector_type(4))) float f32x4;
typedef __attribute__((ext_vector_type(16))) float f32x16;
typedef __attribute__((ext_vector_type(4), aligned(4))) float f32x4u;  // unaligned-tolerant
#if __has_builtin(__builtin_amdgcn_cvt_pk_bf16_f32)
typedef __attribute__((ext_vector_type(2))) __bf16 bf16x2_t;
#endif

union FragU { unsigned u[4]; uint2 u2[2]; uint4 u4; bf16x8 v; };

__device__ __forceinline__ unsigned short f2bf(float f) {
    unsigned u = __builtin_bit_cast(unsigned, f);
    u += 0x7fffu + ((u >> 16) & 1u);
    return (unsigned short)(u >> 16);
}
// pack two fp32 -> bf16 pair (RNE), hi<<16 | lo
__device__ __forceinline__ unsigned bfpack(float lo, float hi) {
#if __has_builtin(__builtin_amdgcn_cvt_pk_bf16_f32)
    bf16x2_t r = __builtin_amdgcn_cvt_pk_bf16_f32(lo, hi);   // S0 -> [15:0]
    return __builtin_bit_cast(unsigned, r);
#else
    unsigned ul = __builtin_bit_cast(unsigned, lo);
    unsigned uh = __builtin_bit_cast(unsigned, hi);
    ul += 0x7fffu + ((ul >> 16) & 1u);
    uh += 0x7fffu + ((uh >> 16) & 1u);
    return __builtin_amdgcn_perm(uh, ul, 0x07060302);
#endif
}
__device__ __forceinline__ float fast_rcp(float x) { return __builtin_amdgcn_rcpf(x); }
__device__ __forceinline__ float fexp2(float x) {
#if __has_builtin(__builtin_amdgcn_exp2f)
    return __builtin_amdgcn_exp2f(x);
#else
    return __expf(x * 0.69314718f);
#endif
}

// Wave-per-row, zero barriers (R3); 32x32 conv1 + vectorized stage A (R4);
// T14 register prefetch (R5); launch_bounds (256,3) (R6 -- best measured,
// ~121us dispatch). R10: + s_setprio(1) around MFMA clusters (T5).
// Mechanism match: independent non-barriered waves at different phases on
// one CU (same regime as learn_hip m191 attn +4-7%, NOT the null lockstep
// GEMM case m190) -- an MFMA-phase wave gets issue priority over VALU-phase
// (stage A) waves, draining the matrix pipe instead of round-robin gaps.
// R7 (BN-fold), R8 (A||C pipeline), R9 (2-row ILP) all measured-regressed
// and are reverted.
__global__ __launch_bounds__(256, 3)
void taylor_cnn_v15_wave(const float* __restrict__ phase, const float* __restrict__ primary,
                         const float* __restrict__ secondary, const float* __restrict__ oddeven,
                         const float* __restrict__ pA, const float* __restrict__ pBp,
                         const float* __restrict__ pT0,
                         const float* __restrict__ bng, const float* __restrict__ bnb,
                         const float* __restrict__ bnm, const float* __restrict__ bnv,
                         const float* __restrict__ w1, const float* __restrict__ b1,
                         const float* __restrict__ w2, const float* __restrict__ b2,
                         const float* __restrict__ fcw, const float* __restrict__ fcb,
                         float* __restrict__ out, int nrows)
{
    // per-wave LDS slices (no cross-wave sharing, no barriers)
    __shared__ __align__(16) unsigned int xs_i[4][XRECS * 2];   // 8.0 KB
    __shared__ __align__(16) unsigned int y1_i[4][YRECS * 4];   // 15.4 KB

    const int tid = threadIdx.x;
    const int l   = tid & 63;
    const int wid = tid >> 6;
    const int row = blockIdx.x * 4 + wid;
    if (row >= nrows) return;                 // wave-uniform; legal (no barriers)
    const long base = (long)row * L_LEN;

    unsigned int* xs = xs_i[wid];
    unsigned int* y1 = y1_i[wid];

    const int n    = l & 15;     // 16x16 MFMA column (conv2 / tail tile)
    const int quad = l >> 4;     // 16x16 MFMA k-block / D row-quad
    const int c    = l & 31;     // 32x32 MFMA column (conv1)
    const int h    = l >> 5;     // 32x32 MFMA half

    const float A  = pA[0];
    const float Bp = pBp[0];
    const float t0 = pT0[0];
    const float A_abs = fabsf(A) + 1e-8f;
    const float rAabs = 1.0f / A_abs;
    const float nBp  = -Bp;
    const float cExp = -72.134766f * rAabs;   // -50*log2(e)*rAabs: exp(-50*dn)=exp2(cExp*depth)

    float inv1, inv2, inv3, gInv0, off0, off1, off2, off3;
    {
        float iv0 = bng[0] / sqrtf(bnv[0] + 1e-5f);
        float iv1 = bng[1] / sqrtf(bnv[1] + 1e-5f);
        float iv2 = bng[2] / sqrtf(bnv[2] + 1e-5f);
        float iv3 = bng[3] / sqrtf(bnv[3] + 1e-5f);
        gInv0 = -A * iv0;                     // gate = relu(1-Bp*d^2); x0 = gate*(-A*iv0)+off0
        inv1 = iv1; inv2 = iv2; inv3 = iv3;
        off0 = bnb[0] - bnm[0] * iv0;
        off1 = bnb[1] - bnm[1] * iv1;
        off2 = bnb[2] - bnm[2] * iv2;
        off3 = bnb[3] - bnm[3] * iv3;
    }

    // ---- conv1 32x32x16 A-fragments: row = l&31 (oc), k = 8*h + j ----
    bf16x8 a32_0, a32_1;
#pragma unroll
    for (int jp = 0; jp < 8; ++jp) {
        int ch_  = jp & 3;
        int tap0 = (jp >> 2) + 2 * h;
        int tap1 = 4 + (jp >> 2) + 2 * h;
        float v0 = (c < 8) ? w1[(c * 4 + ch_) * 7 + tap0] : 0.0f;
        float v1 = (c < 8 && tap1 < 7) ? w1[(c * 4 + ch_) * 7 + tap1] : 0.0f;
        a32_0[jp] = (short)f2bf(v0);
        a32_1[jp] = (short)f2bf(v1);
    }
    // conv1 bias in C operand: D reg r<4 -> row (r&3)+4h
    f32x16 cb32;
#pragma unroll
    for (int r = 0; r < 16; ++r)
        cb32[r] = (r < 4) ? b1[(r & 3) + 4 * h] : 0.0f;

    // ---- 16x16x32 conv1 fragment (tail tile, records 224..239) ----
    bf16x8 a1;
#pragma unroll
    for (int jp = 0; jp < 8; ++jp) {
        int j = quad + 4 * (jp >> 2);
        int cc = jp & 3;
        float v = (n < 8 && j < 7) ? w1[(n * 4 + cc) * 7 + j] : 0.0f;
        a1[jp] = (short)f2bf(v);
    }
    // ---- conv2 fragments ----
    bf16x8 a20, a21;
#pragma unroll
    for (int jp = 0; jp < 8; ++jp) {
        float v0 = w2[(n * 8 + jp) * 5 + quad];
        float v1 = (quad + 4 < 5) ? w2[(n * 8 + jp) * 5 + quad + 4] : 0.0f;
        a20[jp] = (short)f2bf(v0);
        a21[jp] = (short)f2bf(v1);
    }
    f32x4 cb1, cb2;
#pragma unroll
    for (int r = 0; r < 4; ++r) {
        cb1[r] = b1[(quad * 4 + r) & 7];
        cb2[r] = b2[quad * 4 + r];
    }
    // fc weights for the CNN means (per-lane quad's 4 oc)
    float fw0 = fcw[quad * 4 + 0];
    float fw1 = fcw[quad * 4 + 1];
    float fw2 = fcw[quad * 4 + 2];
    float fw3 = fcw[quad * 4 + 3];

    float s_dip = 0.0f, s_fb = 0.0f;          // sum(dip), sum(fb); ing folded out
    float m0 = 0.f, m1 = 0.f, m2 = 0.f, m3 = 0.f;

    // trapz AUC: 200 samples per row -> 4 per lane (last masked to l<8)
    float s_auc = 0.0f;
#pragma unroll
    for (int k = 0; k < 4; ++k) {
        int s = l + 64 * k;
        if (k < 3 || l < 8) {
            float pos = (float)s * (2000.0f / 199.0f);
            int i0 = (int)pos;
            if (i0 > 2000) i0 = 2000;
            int i1 = (i0 + 1 < L_LEN) ? i0 + 1 : 2000;
            float w  = pos - (float)i0;
            float d0 = fmaxf(-primary[base + i0], 0.f);
            float d1 = fmaxf(-primary[base + i1], 0.f);
            float v  = d0 * (1.0f - w) + d1 * w;
            float wt = (s == 0 || s == 199) ? 0.5f : 1.0f;
            s_auc += v * wt;
        }
    }

    // ---- stage A scalar record processor (last chunk only) ----
    auto aRec = [&](int m, int p, bool valid, bool core) {
        float ph = phase[base + p];
        float pf = primary[base + p];
        float sf = secondary[base + p];
        float oe = oddeven[base + p];
        float dd = ph - t0;
        float g  = fmaxf(fmaf(dd * dd, nBp, 1.0f), 0.0f);
        float x0 = fmaf(g,  gInv0, off0);
        float x1 = fmaf(pf, inv1, off1);
        float x2 = fmaf(sf, inv2, off2);
        float x3 = fmaf(oe, inv3, off3);
        unsigned d0 = bfpack(x0, x1);
        unsigned d1 = bfpack(x2, x3);
        if (!valid) { d0 = 0u; d1 = 0u; }
        *(uint2*)&xs[2 * m] = make_uint2(d0, d1);
        float depth = fmaxf(-pf, 0.0f);
        float e   = fexp2(depth * cExp);
        float dip = fast_rcp(fmaf(e, 148.413159f, 1.0f));
        float fb  = fast_rcp(fmaf(e, 2.35385267e17f, 1.0f));
        if (!core) { dip = 0.f; fb = 0.f; }
        s_dip += dip;
        s_fb  += fb;
    };

    const float coreMask = (l >= 4 && l < 60) ? 1.0f : 0.0f;   // records 16..239

    // ---- T14 prefetch: preload chunk 0 ----
    f32x4u ph4, pf4, sf4, oe4;
    {
        int p0 = 4 * l - 16; if (p0 < 0) p0 = 0;
        ph4 = *(const f32x4u*)&phase[base + p0];
        pf4 = *(const f32x4u*)&primary[base + p0];
        sf4 = *(const f32x4u*)&secondary[base + p0];
        oe4 = *(const f32x4u*)&oddeven[base + p0];
    }

    // ---- vector chunks 0..7: A | B | C, wave-synchronous ----
#pragma unroll 1
    for (int ch = 0; ch < NCH - 1; ++ch) {
        const int c0 = ch * CCH;
        const bool isFirst = (ch == 0);

        // issue NEXT chunk's loads now; waitcnt lands at next iteration's
        // stage A, i.e. latency hides under this chunk's B+C
        f32x4u nph, npf, nsf, noe;
        if (ch < NCH - 2) {
            const long pn = base + (c0 + CCH - 16 + 4 * l);
            nph = *(const f32x4u*)&phase[pn];
            npf = *(const f32x4u*)&primary[pn];
            nsf = *(const f32x4u*)&secondary[pn];
            noe = *(const f32x4u*)&oddeven[pn];
        } else {
            nph = ph4; npf = pf4; nsf = sf4; noe = oe4;   // dead
        }

        // ======== stage A (from prefetched regs) ========
        {
            unsigned dw[8];
            float dipA = 0.f, fbA = 0.f;
#pragma unroll
            for (int j = 0; j < 4; ++j) {
                float dd = ph4[j] - t0;
                float g  = fmaxf(fmaf(dd * dd, nBp, 1.0f), 0.0f);
                float x0 = fmaf(g,      gInv0, off0);
                float x1 = fmaf(pf4[j], inv1,  off1);
                float x2 = fmaf(sf4[j], inv2,  off2);
                float x3 = fmaf(oe4[j], inv3,  off3);
                dw[2 * j]     = bfpack(x0, x1);
                dw[2 * j + 1] = bfpack(x2, x3);
                float depth = fmaxf(-pf4[j], 0.0f);
                float e   = fexp2(depth * cExp);
                float dip = fast_rcp(fmaf(e, 148.413159f, 1.0f));
                float fb  = fast_rcp(fmaf(e, 2.35385267e17f, 1.0f));
                dipA += dip;
                fbA  += fb;
            }
            if (isFirst && l < 4) {           // records 0..15 = positions < 0
#pragma unroll
                for (int j = 0; j < 8; ++j) dw[j] = 0u;
            }
            *(uint4*)&xs[8 * l]     = make_uint4(dw[0], dw[1], dw[2], dw[3]);
            *(uint4*)&xs[8 * l + 4] = make_uint4(dw[4], dw[5], dw[6], dw[7]);
            s_dip = fmaf(dipA, coreMask, s_dip);
            s_fb  = fmaf(fbA,  coreMask, s_fb);
        }

        // ======== stage B: conv1 (7x 32-wide + 16-wide tail) ========
        {
            const int cb = c + 2 * h + 5;
#pragma unroll 2
            for (int T = 0; T < 7; ++T) {
                const int R0 = 32 * T + cb;
                FragU b0, b1f;
                b0.u2[0]  = *(const uint2*)&xs[2 * R0];
                b0.u2[1]  = *(const uint2*)&xs[2 * R0 + 2];
                b1f.u2[0] = *(const uint2*)&xs[2 * R0 + 8];
                b1f.u2[1] = *(const uint2*)&xs[2 * R0 + 10];
                __builtin_amdgcn_s_setprio(1);
                f32x16 d = __builtin_amdgcn_mfma_f32_32x32x16_bf16(a32_0, b0.v,  cb32, 0, 0, 0);
                d        = __builtin_amdgcn_mfma_f32_32x32x16_bf16(a32_1, b1f.v, d,    0, 0, 0);
                __builtin_amdgcn_s_setprio(0);
                unsigned w0  = bfpack(fmaxf(d[0], 0.f), fmaxf(d[1], 0.f));
                unsigned w1_ = bfpack(fmaxf(d[2], 0.f), fmaxf(d[3], 0.f));
                if (isFirst && T == 0) {          // pos = c-8 < 0
                    if (c < 8) { w0 = 0u; w1_ = 0u; }
                }
                *(uint2*)&y1[4 * (32 * T + c) + 2 * h] = make_uint2(w0, w1_);
            }
            // tail: y1 records 224..239
            int qb = 224 + n + quad + 5;
            FragU bu;
            bu.u2[0] = *(const uint2*)&xs[2 * qb];
            bu.u2[1] = *(const uint2*)&xs[2 * (qb + 4)];
            __builtin_amdgcn_s_setprio(1);
            f32x4 d = __builtin_amdgcn_mfma_f32_16x16x32_bf16(a1, bu.v, cb1, 0, 0, 0);
            __builtin_amdgcn_s_setprio(0);
            if (l < 32) {
                unsigned w0  = bfpack(fmaxf(d[0], 0.f), fmaxf(d[1], 0.f));
                unsigned w1_ = bfpack(fmaxf(d[2], 0.f), fmaxf(d[3], 0.f));
                *(uint2*)&y1[4 * (224 + n) + 2 * quad] = make_uint2(w0, w1_);
            }
        }

        // ======== stage C: conv2, accumulate channel sums ========
#pragma unroll 2
        for (int t = 0; t < NTC; ++t) {
            int q = 16 * t + n + quad + 6;
            FragU u0, u1;
            u0.u4 = *(const uint4*)&y1[4 * q];
            u1.u4 = *(const uint4*)&y1[4 * (q + 4)];
            __builtin_amdgcn_s_setprio(1);
            f32x4 d = __builtin_amdgcn_mfma_f32_16x16x32_bf16(a20, u0.v, cb2, 0, 0, 0);
            d = __builtin_amdgcn_mfma_f32_16x16x32_bf16(a21, u1.v, d, 0, 0, 0);
            __builtin_amdgcn_s_setprio(0);
            m0 += fmaxf(d[0], 0.f);
            m1 += fmaxf(d[1], 0.f);
            m2 += fmaxf(d[2], 0.f);
            m3 += fmaxf(d[3], 0.f);
        }

        ph4 = nph; pf4 = npf; sf4 = nsf; oe4 = noe;
    }

    // ---- last chunk (ch = 8): scalar A, straddle-masked B, masked C ----
    {
        const int c0 = (NCH - 1) * CCH;       // 1792
        const int pb = c0 - 16;               // 1776

        // stage A: per-record valid/core
        {
            bool co0 = (l >= 16);
            int  p3  = pb + l + 192;
            bool v3  = (l < 33);              // p <= 2000
            bool co3 = v3 && (l < 48);
            if (p3 > 2000) p3 = 2000;
            aRec(l,        pb + l,       true, co0);
            aRec(l + 64,   pb + l + 64,  true, true);
            aRec(l + 128,  pb + l + 128, true, true);
            aRec(l + 192,  p3,           v3,   co3);
        }

        // stage B: 7 tiles; T==6 straddles pos 2000 (c>24 invalid)
        {
            const int cb = c + 2 * h + 5;
#pragma unroll 2
            for (int T = 0; T < 7; ++T) {
                const int R0 = 32 * T + cb;
                FragU b0, b1f;
                b0.u2[0]  = *(const uint2*)&xs[2 * R0];
                b0.u2[1]  = *(const uint2*)&xs[2 * R0 + 2];
                b1f.u2[0] = *(const uint2*)&xs[2 * R0 + 8];
                b1f.u2[1] = *(const uint2*)&xs[2 * R0 + 10];
                __builtin_amdgcn_s_setprio(1);
                f32x16 d = __builtin_amdgcn_mfma_f32_32x32x16_bf16(a32_0, b0.v,  cb32, 0, 0, 0);
                d        = __builtin_amdgcn_mfma_f32_32x32x16_bf16(a32_1, b1f.v, d,    0, 0, 0);
                __builtin_amdgcn_s_setprio(0);
                unsigned w0  = bfpack(fmaxf(d[0], 0.f), fmaxf(d[1], 0.f));
                unsigned w1_ = bfpack(fmaxf(d[2], 0.f), fmaxf(d[3], 0.f));
                if (T == 6 && c > 24) { w0 = 0u; w1_ = 0u; }   // pos = 1976+c > 2000
                *(uint2*)&y1[4 * (32 * T + c) + 2 * h] = make_uint2(w0, w1_);
            }
            // tail records 224..239: positions 2008..2023, all beyond row
            if (l < 32)
                *(uint2*)&y1[4 * (224 + n) + 2 * quad] = make_uint2(0u, 0u);
        }

        // stage C: tile 13 outputs 2000..2015 -> only n==0 valid
#pragma unroll 2
        for (int t = 0; t < NTC; ++t) {
            int q = 16 * t + n + quad + 6;
            FragU u0, u1;
            u0.u4 = *(const uint4*)&y1[4 * q];
            u1.u4 = *(const uint4*)&y1[4 * (q + 4)];
            __builtin_amdgcn_s_setprio(1);
            f32x4 d = __builtin_amdgcn_mfma_f32_16x16x32_bf16(a20, u0.v, cb2, 0, 0, 0);
            d = __builtin_amdgcn_mfma_f32_16x16x32_bf16(a21, u1.v, d, 0, 0, 0);
            __builtin_amdgcn_s_setprio(0);
            if (t == 13) {
                float msk = (n == 0) ? 1.0f : 0.0f;
                m0 = fmaf(fmaxf(d[0], 0.f), msk, m0);
                m1 = fmaf(fmaxf(d[1], 0.f), msk, m1);
                m2 = fmaf(fmaxf(d[2], 0.f), msk, m2);
                m3 = fmaf(fmaxf(d[3], 0.f), msk, m3);
            } else {
                m0 += fmaxf(d[0], 0.f);
                m1 += fmaxf(d[1], 0.f);
                m2 += fmaxf(d[2], 0.f);
                m3 += fmaxf(d[3], 0.f);
            }
        }
    }

    // ---- per-wave reductions (no LDS, no barriers) ----
#pragma unroll
    for (int dlt = 8; dlt >= 1; dlt >>= 1) {     // sum over n within 16-group
        m0 += __shfl_xor(m0, dlt);
        m1 += __shfl_xor(m1, dlt);
        m2 += __shfl_xor(m2, dlt);
        m3 += __shfl_xor(m3, dlt);
    }
    float part = m0 * fw0 + m1 * fw1 + m2 * fw2 + m3 * fw3;
    part = (n == 0) ? part : 0.0f;
    part += __shfl_xor(part, 16);
    part += __shfl_xor(part, 32);
#pragma unroll
    for (int dlt = 32; dlt >= 1; dlt >>= 1) {
        s_dip += __shfl_xor(s_dip, dlt);
        s_fb  += __shfl_xor(s_fb,  dlt);
        s_auc += __shfl_xor(s_auc, dlt);
    }

    if (l == 0) {
        float Sing = s_dip - s_fb;               // sum(ing) = sum(dip) - sum(fb)
        float logit = fcb[0] + part * (1.0f / 2001.0f);
        float auc_raw  = (float)(2.0 / 199.0) * s_auc;
        float auc_norm = auc_raw / A_abs;
        float m_ing = Sing / 2001.0f;
        float m_fb  = s_fb  / 2001.0f;
        float t14   = s_dip / 2001.0f + 1e-8f;   // (Sing+Sfb) == Sdip
        float t12   = m_ing / t14;

        logit += Bp       * fcw[16]
               + auc_raw  * fcw[17]
               + auc_norm * fcw[18]
               + t12      * fcw[19]
               + m_fb     * fcw[20];

        out[row] = 1.0f / (1.0f + expf(-logit));
    }
}

extern "C" void kernel_launch(void* const* d_in, const int* in_sizes, int n_in,
                              void* d_out, int out_size, void* d_ws, size_t ws_size,
                              hipStream_t stream) {
    const float* phase     = (const float*)d_in[0];
    const float* primary   = (const float*)d_in[1];
    const float* secondary = (const float*)d_in[2];
    const float* oddeven   = (const float*)d_in[3];
    const float* pA        = (const float*)d_in[4];
    const float* pBp       = (const float*)d_in[5];
    const float* pT0       = (const float*)d_in[6];
    const float* bng       = (const float*)d_in[7];
    const float* bnb       = (const float*)d_in[8];
    const float* bnm       = (const float*)d_in[9];
    const float* bnv       = (const float*)d_in[10];
    const float* w1        = (const float*)d_in[11];
    const float* b1        = (const float*)d_in[12];
    const float* w2        = (const float*)d_in[13];
    const float* b2        = (const float*)d_in[14];
    const float* fcw       = (const float*)d_in[15];
    const float* fcb       = (const float*)d_in[16];
    float* out = (float*)d_out;

    int nrows = in_sizes[0] / L_LEN;   // 8192
    dim3 grid((nrows + 3) / 4), block(256);
    hipLaunchKernelGGL(taylor_cnn_v15_wave, grid, block, 0, stream,
                       phase, primary, secondary, oddeven, pA, pBp, pT0,
                       bng, bnb, bnm, bnv, w1, b1, w2, b2, fcw, fcb, out, nrows);
}

// Round 11
// 278.122 us; speedup vs baseline: 1.1416x; 1.0227x over previous
//
#include <hip/hip_runtime.h>
#include <math.h>

#define L_LEN 2001
#define CCH 224           // positions per chunk per wave
#define NCH 9             // chunks: 9*224 = 2016 >= 2001
#define XRECS 256         // xs records per chunk (CCH+32) -> exactly 4 per lane
#define YRECS 240         // y1 records per chunk (CCH+16)
#define NTC 14            // conv2 tiles per chunk (CCH/16 outputs)

typedef __attribute__((ext_vector_type(8))) short bf16x8;
typedef __attribute__((ext_vector_type(4))) float f32x4;
typedef __attribute__((ext_vector_type(16))) float f32x16;
typedef __attribute__((ext_vector_type(4), aligned(4))) float f32x4u;  // unaligned-tolerant
#if __has_builtin(__builtin_amdgcn_cvt_pk_bf16_f32)
typedef __attribute__((ext_vector_type(2))) __bf16 bf16x2_t;
#endif

union FragU { unsigned u[4]; uint2 u2[2]; uint4 u4; bf16x8 v; };

__device__ __forceinline__ unsigned short f2bf(float f) {
    unsigned u = __builtin_bit_cast(unsigned, f);
    u += 0x7fffu + ((u >> 16) & 1u);
    return (unsigned short)(u >> 16);
}
// pack two fp32 -> bf16 pair (RNE), hi<<16 | lo
__device__ __forceinline__ unsigned bfpack(float lo, float hi) {
#if __has_builtin(__builtin_amdgcn_cvt_pk_bf16_f32)
    bf16x2_t r = __builtin_amdgcn_cvt_pk_bf16_f32(lo, hi);   // S0 -> [15:0]
    return __builtin_bit_cast(unsigned, r);
#else
    unsigned ul = __builtin_bit_cast(unsigned, lo);
    unsigned uh = __builtin_bit_cast(unsigned, hi);
    ul += 0x7fffu + ((ul >> 16) & 1u);
    uh += 0x7fffu + ((uh >> 16) & 1u);
    return __builtin_amdgcn_perm(uh, ul, 0x07060302);
#endif
}
__device__ __forceinline__ float fast_rcp(float x) { return __builtin_amdgcn_rcpf(x); }
__device__ __forceinline__ float fexp2(float x) {
#if __has_builtin(__builtin_amdgcn_exp2f)
    return __builtin_amdgcn_exp2f(x);
#else
    return __expf(x * 0.69314718f);
#endif
}

// FINAL (R11 = R6 restored; best measured ~121us dispatch).
// Structure: wave-per-row, zero barriers (R3); conv1 as 32x32x16 MFMA +
// float4-vectorized stage A (R4); T14 register prefetch of next chunk
// (R5); launch_bounds(256,3) so the prefetch fits without scratch spill
// (R6; (256,4) spilled ~12MB/dispatch, R5).
// Falsified levers (each measured, then reverted): occupancy scaling
// (R0-R2,R6 -- no causal wall effect), BN-fold/packed-accum (R7, -7us),
// cross-stage SW pipeline (R8 -- A||C ds streams false-couple on in-order
// lgkmcnt), 2-row-per-wave ILP (R9, reg-pressure kills TLP, -40us),
// s_setprio around short MFMA clusters (R10, -5us; windows too small).
// Residual profile: VALU 57% / DS ~40% / MFMA 24%, no pipe saturated --
// intra-wave dependency latency; structural limit of this decomposition
// at HIP source level.
__global__ __launch_bounds__(256, 3)
void taylor_cnn_v11_wave(const float* __restrict__ phase, const float* __restrict__ primary,
                         const float* __restrict__ secondary, const float* __restrict__ oddeven,
                         const float* __restrict__ pA, const float* __restrict__ pBp,
                         const float* __restrict__ pT0,
                         const float* __restrict__ bng, const float* __restrict__ bnb,
                         const float* __restrict__ bnm, const float* __restrict__ bnv,
                         const float* __restrict__ w1, const float* __restrict__ b1,
                         const float* __restrict__ w2, const float* __restrict__ b2,
                         const float* __restrict__ fcw, const float* __restrict__ fcb,
                         float* __restrict__ out, int nrows)
{
    // per-wave LDS slices (no cross-wave sharing, no barriers)
    __shared__ __align__(16) unsigned int xs_i[4][XRECS * 2];   // 8.0 KB
    __shared__ __align__(16) unsigned int y1_i[4][YRECS * 4];   // 15.4 KB

    const int tid = threadIdx.x;
    const int l   = tid & 63;
    const int wid = tid >> 6;
    const int row = blockIdx.x * 4 + wid;
    if (row >= nrows) return;                 // wave-uniform; legal (no barriers)
    const long base = (long)row * L_LEN;

    unsigned int* xs = xs_i[wid];
    unsigned int* y1 = y1_i[wid];

    const int n    = l & 15;     // 16x16 MFMA column (conv2 / tail tile)
    const int quad = l >> 4;     // 16x16 MFMA k-block / D row-quad
    const int c    = l & 31;     // 32x32 MFMA column (conv1)
    const int h    = l >> 5;     // 32x32 MFMA half

    const float A  = pA[0];
    const float Bp = pBp[0];
    const float t0 = pT0[0];
    const float A_abs = fabsf(A) + 1e-8f;
    const float rAabs = 1.0f / A_abs;
    const float nBp  = -Bp;
    const float cExp = -72.134766f * rAabs;   // -50*log2(e)*rAabs: exp(-50*dn)=exp2(cExp*depth)

    float inv1, inv2, inv3, gInv0, off0, off1, off2, off3;
    {
        float iv0 = bng[0] / sqrtf(bnv[0] + 1e-5f);
        float iv1 = bng[1] / sqrtf(bnv[1] + 1e-5f);
        float iv2 = bng[2] / sqrtf(bnv[2] + 1e-5f);
        float iv3 = bng[3] / sqrtf(bnv[3] + 1e-5f);
        gInv0 = -A * iv0;                     // gate = relu(1-Bp*d^2); x0 = gate*(-A*iv0)+off0
        inv1 = iv1; inv2 = iv2; inv3 = iv3;
        off0 = bnb[0] - bnm[0] * iv0;
        off1 = bnb[1] - bnm[1] * iv1;
        off2 = bnb[2] - bnm[2] * iv2;
        off3 = bnb[3] - bnm[3] * iv3;
    }

    // ---- conv1 32x32x16 A-fragments: row = l&31 (oc), k = 8*h + j ----
    bf16x8 a32_0, a32_1;
#pragma unroll
    for (int jp = 0; jp < 8; ++jp) {
        int ch_  = jp & 3;
        int tap0 = (jp >> 2) + 2 * h;
        int tap1 = 4 + (jp >> 2) + 2 * h;
        float v0 = (c < 8) ? w1[(c * 4 + ch_) * 7 + tap0] : 0.0f;
        float v1 = (c < 8 && tap1 < 7) ? w1[(c * 4 + ch_) * 7 + tap1] : 0.0f;
        a32_0[jp] = (short)f2bf(v0);
        a32_1[jp] = (short)f2bf(v1);
    }
    // conv1 bias in C operand: D reg r<4 -> row (r&3)+4h
    f32x16 cb32;
#pragma unroll
    for (int r = 0; r < 16; ++r)
        cb32[r] = (r < 4) ? b1[(r & 3) + 4 * h] : 0.0f;

    // ---- 16x16x32 conv1 fragment (tail tile, records 224..239) ----
    bf16x8 a1;
#pragma unroll
    for (int jp = 0; jp < 8; ++jp) {
        int j = quad + 4 * (jp >> 2);
        int cc = jp & 3;
        float v = (n < 8 && j < 7) ? w1[(n * 4 + cc) * 7 + j] : 0.0f;
        a1[jp] = (short)f2bf(v);
    }
    // ---- conv2 fragments ----
    bf16x8 a20, a21;
#pragma unroll
    for (int jp = 0; jp < 8; ++jp) {
        float v0 = w2[(n * 8 + jp) * 5 + quad];
        float v1 = (quad + 4 < 5) ? w2[(n * 8 + jp) * 5 + quad + 4] : 0.0f;
        a20[jp] = (short)f2bf(v0);
        a21[jp] = (short)f2bf(v1);
    }
    f32x4 cb1, cb2;
#pragma unroll
    for (int r = 0; r < 4; ++r) {
        cb1[r] = b1[(quad * 4 + r) & 7];
        cb2[r] = b2[quad * 4 + r];
    }
    // fc weights for the CNN means (per-lane quad's 4 oc)
    float fw0 = fcw[quad * 4 + 0];
    float fw1 = fcw[quad * 4 + 1];
    float fw2 = fcw[quad * 4 + 2];
    float fw3 = fcw[quad * 4 + 3];

    float s_dip = 0.0f, s_fb = 0.0f;          // sum(dip), sum(fb); ing folded out
    float m0 = 0.f, m1 = 0.f, m2 = 0.f, m3 = 0.f;

    // trapz AUC: 200 samples per row -> 4 per lane (last masked to l<8)
    float s_auc = 0.0f;
#pragma unroll
    for (int k = 0; k < 4; ++k) {
        int s = l + 64 * k;
        if (k < 3 || l < 8) {
            float pos = (float)s * (2000.0f / 199.0f);
            int i0 = (int)pos;
            if (i0 > 2000) i0 = 2000;
            int i1 = (i0 + 1 < L_LEN) ? i0 + 1 : 2000;
            float w  = pos - (float)i0;
            float d0 = fmaxf(-primary[base + i0], 0.f);
            float d1 = fmaxf(-primary[base + i1], 0.f);
            float v  = d0 * (1.0f - w) + d1 * w;
            float wt = (s == 0 || s == 199) ? 0.5f : 1.0f;
            s_auc += v * wt;
        }
    }

    // ---- stage A scalar record processor (last chunk only) ----
    auto aRec = [&](int m, int p, bool valid, bool core) {
        float ph = phase[base + p];
        float pf = primary[base + p];
        float sf = secondary[base + p];
        float oe = oddeven[base + p];
        float dd = ph - t0;
        float g  = fmaxf(fmaf(dd * dd, nBp, 1.0f), 0.0f);
        float x0 = fmaf(g,  gInv0, off0);
        float x1 = fmaf(pf, inv1, off1);
        float x2 = fmaf(sf, inv2, off2);
        float x3 = fmaf(oe, inv3, off3);
        unsigned d0 = bfpack(x0, x1);
        unsigned d1 = bfpack(x2, x3);
        if (!valid) { d0 = 0u; d1 = 0u; }
        *(uint2*)&xs[2 * m] = make_uint2(d0, d1);
        float depth = fmaxf(-pf, 0.0f);
        float e   = fexp2(depth * cExp);
        float dip = fast_rcp(fmaf(e, 148.413159f, 1.0f));
        float fb  = fast_rcp(fmaf(e, 2.35385267e17f, 1.0f));
        if (!core) { dip = 0.f; fb = 0.f; }
        s_dip += dip;
        s_fb  += fb;
    };

    const float coreMask = (l >= 4 && l < 60) ? 1.0f : 0.0f;   // records 16..239

    // ---- T14 prefetch: preload chunk 0 ----
    f32x4u ph4, pf4, sf4, oe4;
    {
        int p0 = 4 * l - 16; if (p0 < 0) p0 = 0;
        ph4 = *(const f32x4u*)&phase[base + p0];
        pf4 = *(const f32x4u*)&primary[base + p0];
        sf4 = *(const f32x4u*)&secondary[base + p0];
        oe4 = *(const f32x4u*)&oddeven[base + p0];
    }

    // ---- vector chunks 0..7: A | B | C, wave-synchronous ----
#pragma unroll 1
    for (int ch = 0; ch < NCH - 1; ++ch) {
        const int c0 = ch * CCH;
        const bool isFirst = (ch == 0);

        // issue NEXT chunk's loads now; waitcnt lands at next iteration's
        // stage A, i.e. latency hides under this chunk's B+C
        f32x4u nph, npf, nsf, noe;
        if (ch < NCH - 2) {
            const long pn = base + (c0 + CCH - 16 + 4 * l);
            nph = *(const f32x4u*)&phase[pn];
            npf = *(const f32x4u*)&primary[pn];
            nsf = *(const f32x4u*)&secondary[pn];
            noe = *(const f32x4u*)&oddeven[pn];
        } else {
            nph = ph4; npf = pf4; nsf = sf4; noe = oe4;   // dead
        }

        // ======== stage A (from prefetched regs) ========
        {
            unsigned dw[8];
            float dipA = 0.f, fbA = 0.f;
#pragma unroll
            for (int j = 0; j < 4; ++j) {
                float dd = ph4[j] - t0;
                float g  = fmaxf(fmaf(dd * dd, nBp, 1.0f), 0.0f);
                float x0 = fmaf(g,      gInv0, off0);
                float x1 = fmaf(pf4[j], inv1,  off1);
                float x2 = fmaf(sf4[j], inv2,  off2);
                float x3 = fmaf(oe4[j], inv3,  off3);
                dw[2 * j]     = bfpack(x0, x1);
                dw[2 * j + 1] = bfpack(x2, x3);
                float depth = fmaxf(-pf4[j], 0.0f);
                float e   = fexp2(depth * cExp);
                float dip = fast_rcp(fmaf(e, 148.413159f, 1.0f));
                float fb  = fast_rcp(fmaf(e, 2.35385267e17f, 1.0f));
                dipA += dip;
                fbA  += fb;
            }
            if (isFirst && l < 4) {           // records 0..15 = positions < 0
#pragma unroll
                for (int j = 0; j < 8; ++j) dw[j] = 0u;
            }
            *(uint4*)&xs[8 * l]     = make_uint4(dw[0], dw[1], dw[2], dw[3]);
            *(uint4*)&xs[8 * l + 4] = make_uint4(dw[4], dw[5], dw[6], dw[7]);
            s_dip = fmaf(dipA, coreMask, s_dip);
            s_fb  = fmaf(fbA,  coreMask, s_fb);
        }

        // ======== stage B: conv1 (7x 32-wide + 16-wide tail) ========
        {
            const int cb = c + 2 * h + 5;
#pragma unroll 2
            for (int T = 0; T < 7; ++T) {
                const int R0 = 32 * T + cb;
                FragU b0, b1f;
                b0.u2[0]  = *(const uint2*)&xs[2 * R0];
                b0.u2[1]  = *(const uint2*)&xs[2 * R0 + 2];
                b1f.u2[0] = *(const uint2*)&xs[2 * R0 + 8];
                b1f.u2[1] = *(const uint2*)&xs[2 * R0 + 10];
                f32x16 d = __builtin_amdgcn_mfma_f32_32x32x16_bf16(a32_0, b0.v,  cb32, 0, 0, 0);
                d        = __builtin_amdgcn_mfma_f32_32x32x16_bf16(a32_1, b1f.v, d,    0, 0, 0);
                unsigned w0  = bfpack(fmaxf(d[0], 0.f), fmaxf(d[1], 0.f));
                unsigned w1_ = bfpack(fmaxf(d[2], 0.f), fmaxf(d[3], 0.f));
                if (isFirst && T == 0) {          // pos = c-8 < 0
                    if (c < 8) { w0 = 0u; w1_ = 0u; }
                }
                *(uint2*)&y1[4 * (32 * T + c) + 2 * h] = make_uint2(w0, w1_);
            }
            // tail: y1 records 224..239
            int qb = 224 + n + quad + 5;
            FragU bu;
            bu.u2[0] = *(const uint2*)&xs[2 * qb];
            bu.u2[1] = *(const uint2*)&xs[2 * (qb + 4)];
            f32x4 d = __builtin_amdgcn_mfma_f32_16x16x32_bf16(a1, bu.v, cb1, 0, 0, 0);
            if (l < 32) {
                unsigned w0  = bfpack(fmaxf(d[0], 0.f), fmaxf(d[1], 0.f));
                unsigned w1_ = bfpack(fmaxf(d[2], 0.f), fmaxf(d[3], 0.f));
                *(uint2*)&y1[4 * (224 + n) + 2 * quad] = make_uint2(w0, w1_);
            }
        }

        // ======== stage C: conv2, accumulate channel sums ========
#pragma unroll 2
        for (int t = 0; t < NTC; ++t) {
            int q = 16 * t + n + quad + 6;
            FragU u0, u1;
            u0.u4 = *(const uint4*)&y1[4 * q];
            u1.u4 = *(const uint4*)&y1[4 * (q + 4)];
            f32x4 d = __builtin_amdgcn_mfma_f32_16x16x32_bf16(a20, u0.v, cb2, 0, 0, 0);
            d = __builtin_amdgcn_mfma_f32_16x16x32_bf16(a21, u1.v, d, 0, 0, 0);
            m0 += fmaxf(d[0], 0.f);
            m1 += fmaxf(d[1], 0.f);
            m2 += fmaxf(d[2], 0.f);
            m3 += fmaxf(d[3], 0.f);
        }

        ph4 = nph; pf4 = npf; sf4 = nsf; oe4 = noe;
    }

    // ---- last chunk (ch = 8): scalar A, straddle-masked B, masked C ----
    {
        const int c0 = (NCH - 1) * CCH;       // 1792
        const int pb = c0 - 16;               // 1776

        // stage A: per-record valid/core
        {
            bool co0 = (l >= 16);
            int  p3  = pb + l + 192;
            bool v3  = (l < 33);              // p <= 2000
            bool co3 = v3 && (l < 48);
            if (p3 > 2000) p3 = 2000;
            aRec(l,        pb + l,       true, co0);
            aRec(l + 64,   pb + l + 64,  true, true);
            aRec(l + 128,  pb + l + 128, true, true);
            aRec(l + 192,  p3,           v3,   co3);
        }

        // stage B: 7 tiles; T==6 straddles pos 2000 (c>24 invalid)
        {
            const int cb = c + 2 * h + 5;
#pragma unroll 2
            for (int T = 0; T < 7; ++T) {
                const int R0 = 32 * T + cb;
                FragU b0, b1f;
                b0.u2[0]  = *(const uint2*)&xs[2 * R0];
                b0.u2[1]  = *(const uint2*)&xs[2 * R0 + 2];
                b1f.u2[0] = *(const uint2*)&xs[2 * R0 + 8];
                b1f.u2[1] = *(const uint2*)&xs[2 * R0 + 10];
                f32x16 d = __builtin_amdgcn_mfma_f32_32x32x16_bf16(a32_0, b0.v,  cb32, 0, 0, 0);
                d        = __builtin_amdgcn_mfma_f32_32x32x16_bf16(a32_1, b1f.v, d,    0, 0, 0);
                unsigned w0  = bfpack(fmaxf(d[0], 0.f), fmaxf(d[1], 0.f));
                unsigned w1_ = bfpack(fmaxf(d[2], 0.f), fmaxf(d[3], 0.f));
                if (T == 6 && c > 24) { w0 = 0u; w1_ = 0u; }   // pos = 1976+c > 2000
                *(uint2*)&y1[4 * (32 * T + c) + 2 * h] = make_uint2(w0, w1_);
            }
            // tail records 224..239: positions 2008..2023, all beyond row
            if (l < 32)
                *(uint2*)&y1[4 * (224 + n) + 2 * quad] = make_uint2(0u, 0u);
        }

        // stage C: tile 13 outputs 2000..2015 -> only n==0 valid
#pragma unroll 2
        for (int t = 0; t < NTC; ++t) {
            int q = 16 * t + n + quad + 6;
            FragU u0, u1;
            u0.u4 = *(const uint4*)&y1[4 * q];
            u1.u4 = *(const uint4*)&y1[4 * (q + 4)];
            f32x4 d = __builtin_amdgcn_mfma_f32_16x16x32_bf16(a20, u0.v, cb2, 0, 0, 0);
            d = __builtin_amdgcn_mfma_f32_16x16x32_bf16(a21, u1.v, d, 0, 0, 0);
            if (t == 13) {
                float msk = (n == 0) ? 1.0f : 0.0f;
                m0 = fmaf(fmaxf(d[0], 0.f), msk, m0);
                m1 = fmaf(fmaxf(d[1], 0.f), msk, m1);
                m2 = fmaf(fmaxf(d[2], 0.f), msk, m2);
                m3 = fmaf(fmaxf(d[3], 0.f), msk, m3);
            } else {
                m0 += fmaxf(d[0], 0.f);
                m1 += fmaxf(d[1], 0.f);
                m2 += fmaxf(d[2], 0.f);
                m3 += fmaxf(d[3], 0.f);
            }
        }
    }

    // ---- per-wave reductions (no LDS, no barriers) ----
#pragma unroll
    for (int dlt = 8; dlt >= 1; dlt >>= 1) {     // sum over n within 16-group
        m0 += __shfl_xor(m0, dlt);
        m1 += __shfl_xor(m1, dlt);
        m2 += __shfl_xor(m2, dlt);
        m3 += __shfl_xor(m3, dlt);
    }
    float part = m0 * fw0 + m1 * fw1 + m2 * fw2 + m3 * fw3;
    part = (n == 0) ? part : 0.0f;
    part += __shfl_xor(part, 16);
    part += __shfl_xor(part, 32);
#pragma unroll
    for (int dlt = 32; dlt >= 1; dlt >>= 1) {
        s_dip += __shfl_xor(s_dip, dlt);
        s_fb  += __shfl_xor(s_fb,  dlt);
        s_auc += __shfl_xor(s_auc, dlt);
    }

    if (l == 0) {
        float Sing = s_dip - s_fb;               // sum(ing) = sum(dip) - sum(fb)
        float logit = fcb[0] + part * (1.0f / 2001.0f);
        float auc_raw  = (float)(2.0 / 199.0) * s_auc;
        float auc_norm = auc_raw / A_abs;
        float m_ing = Sing / 2001.0f;
        float m_fb  = s_fb  / 2001.0f;
        float t14   = s_dip / 2001.0f + 1e-8f;   // (Sing+Sfb) == Sdip
        float t12   = m_ing / t14;

        logit += Bp       * fcw[16]
               + auc_raw  * fcw[17]
               + auc_norm * fcw[18]
               + t12      * fcw[19]
               + m_fb     * fcw[20];

        out[row] = 1.0f / (1.0f + expf(-logit));
    }
}

extern "C" void kernel_launch(void* const* d_in, const int* in_sizes, int n_in,
                              void* d_out, int out_size, void* d_ws, size_t ws_size,
                              hipStream_t stream) {
    const float* phase     = (const float*)d_in[0];
    const float* primary   = (const float*)d_in[1];
    const float* secondary = (const float*)d_in[2];
    const float* oddeven   = (const float*)d_in[3];
    const float* pA        = (const float*)d_in[4];
    const float* pBp       = (const float*)d_in[5];
    const float* pT0       = (const float*)d_in[6];
    const float* bng       = (const float*)d_in[7];
    const float* bnb       = (const float*)d_in[8];
    const float* bnm       = (const float*)d_in[9];
    const float* bnv       = (const float*)d_in[10];
    const float* w1        = (const float*)d_in[11];
    const float* b1        = (const float*)d_in[12];
    const float* w2        = (const float*)d_in[13];
    const float* b2        = (const float*)d_in[14];
    const float* fcw       = (const float*)d_in[15];
    const float* fcb       = (const float*)d_in[16];
    float* out = (float*)d_out;

    int nrows = in_sizes[0] / L_LEN;   // 8192
    dim3 grid((nrows + 3) / 4), block(256);
    hipLaunchKernelGGL(taylor_cnn_v11_wave, grid, block, 0, stream,
                       phase, primary, secondary, oddeven, pA, pBp, pT0,
                       bng, bnb, bnm, bnv, w1, b1, w2, b2, fcw, fcb, out, nrows);
}